// Round 4
// baseline (608.634 us; speedup 1.0000x reference)
//
#include <hip/hip_runtime.h>
#include <hip/hip_bf16.h>
#include <cstdint>
#include <cstddef>

// Problem constants
#define NP     100352      // 32*56*56 total pixels
#define HW     3136        // 56*56
#define CDIM   384
#define C3     1152        // 3*384
#define NHEAD  12
#define HD     32          // head dim
#define NWIN   2048        // 32 * 8 * 8 windows

typedef __attribute__((ext_vector_type(8))) short bf16x8;
typedef __attribute__((ext_vector_type(4))) float f32x4;

static __device__ __forceinline__ float bf2f(unsigned short u) {
    union { float f; uint32_t i; } v; v.i = ((uint32_t)u) << 16; return v.f;
}
static __device__ __forceinline__ unsigned short f2bf(float f) {
    union { float f; uint32_t i; } v; v.f = f;
    uint32_t r = v.i + 0x7FFFu + ((v.i >> 16) & 1u);   // round-nearest-even
    return (unsigned short)(r >> 16);
}
// pack two f32 -> bf16 pair (round-half-up; lo half = a)
static __device__ __forceinline__ uint32_t pk2(float a, float b) {
    union { float f; uint32_t u; } x, y; x.f = a; y.f = b;
    return ((x.u + 0x8000u) >> 16) | ((y.u + 0x8000u) & 0xffff0000u);
}

// async global->LDS, 16B per lane; LDS dest = uniform base + lane*16
static __device__ __forceinline__ void gld_lds16(const void* g, void* l) {
    __builtin_amdgcn_global_load_lds(
        (const __attribute__((address_space(1))) void*)g,
        (__attribute__((address_space(3))) void*)l, 16, 0, 0);
}

// ---------------------------------------------------------------------------
// Kernel 1: fp32 -> bf16 weight conversion (vectorized x4)
// ---------------------------------------------------------------------------
__global__ __launch_bounds__(256) void cvt_f32_bf16(
    const float* __restrict__ src, unsigned short* __restrict__ dst, int n4) {
    int i = blockIdx.x * blockDim.x + threadIdx.x;
    if (i < n4) {
        float4 v = ((const float4*)src)[i];
        ushort4 r;
        r.x = f2bf(v.x); r.y = f2bf(v.y); r.z = f2bf(v.z); r.w = f2bf(v.w);
        ((ushort4*)dst)[i] = r;
    }
}

// ---------------------------------------------------------------------------
// Kernel 1b: precompute bias_t[h][query][key] fp32 (64x64 padded, / scale,
// -1e30 on pads so softmax masking is free)
// ---------------------------------------------------------------------------
__global__ __launch_bounds__(256) void bias_pre(
    const float* __restrict__ btab, float* __restrict__ bias_t) {
    int idx = blockIdx.x * 256 + threadIdx.x;
    int h = idx >> 12, query = (idx >> 6) & 63, key = idx & 63;
    float v = -1e30f;
    if (query < 49 && key < 49) {
        int ri = query / 7, rj = query % 7, mi = key / 7, mj = key % 7;
        v = btab[((ri - mi + 6) * 13 + (rj - mj + 6)) * NHEAD + h] * 5.656854249492381f;
    }
    bias_t[idx] = v;
}

// ---------------------------------------------------------------------------
// Kernel 2: transpose x (B, C, HW) fp32 -> xt (B*HW, C) bf16.
// 64x64 tiles; grid (49, 6, 32), block 256. HBM-bound: float4 loads (1 KB per
// wave instr), LDS fp32 tile [64][68] (b128 writes conflict-free), bf16x8
// coalesced stores (256 B runs per 16 lanes).
// ---------------------------------------------------------------------------
__global__ __launch_bounds__(256) void transpose_x2(
    const float* __restrict__ x, unsigned short* __restrict__ xt) {
    __shared__ __align__(16) float tile[64][68];
    int b   = blockIdx.z;
    int c0  = blockIdx.y * 64;
    int hw0 = blockIdx.x * 64;
    int t = threadIdx.x;
    int cl = t >> 2, qi = t & 3;
    const float* xp = x + (size_t)b * CDIM * HW + (size_t)(c0 + cl) * HW + hw0;
#pragma unroll
    for (int j = 0; j < 4; j++) {
        float4 v = *(const float4*)(xp + 4 * (qi + 4 * j));
        *(float4*)(&tile[cl][4 * (qi + 4 * j)]) = v;
    }
    __syncthreads();
    unsigned short* xtp = xt + ((size_t)b * HW + hw0) * CDIM + c0;
#pragma unroll
    for (int i = 0; i < 2; i++) {
        int idx = t + 256 * i;
        int pl = idx >> 3, ch = idx & 7;
        unsigned short pk[8];
#pragma unroll
        for (int r = 0; r < 8; r++)
            pk[r] = f2bf(tile[8 * ch + r][pl]);
        *(uint4*)(xtp + (size_t)pl * CDIM + 8 * ch) = *(const uint4*)pk;
    }
}

// ---------------------------------------------------------------------------
// MFMA GEMM main loop (m97 structure). K = 384 fixed.
// ---------------------------------------------------------------------------
static __device__ __forceinline__ void gemm_main(
    const unsigned short* __restrict__ A, const unsigned short* __restrict__ Bt,
    int m0, int n0, unsigned short* As, unsigned short* Bs, f32x4 acc[4][4]) {

    int tid  = threadIdx.x;
    int wv   = tid >> 6;
    int lane = tid & 63;
    int wr = wv >> 1, wc = wv & 1;
    int lrow = lane & 15, lq = lane >> 4;

#pragma unroll
    for (int mi = 0; mi < 4; mi++)
#pragma unroll
        for (int ni = 0; ni < 4; ni++)
            acc[mi][ni] = (f32x4){0.f, 0.f, 0.f, 0.f};

    for (int kt = 0; kt < 12; kt++) {   // K = 384 = 12 * 32
#pragma unroll
        for (int i = 0; i < 2; i++) {
            int ch  = wv * 2 + i;
            int row = ch * 16 + (lane >> 2);
            int seg = lane & 3;
            gld_lds16(A  + (size_t)(m0 + row) * 384 + kt * 32 + seg * 8, As + ch * 512);
            gld_lds16(Bt + (size_t)(n0 + row) * 384 + kt * 32 + seg * 8, Bs + ch * 512);
        }
        __syncthreads();

        bf16x8 af[4], bfr[4];
#pragma unroll
        for (int mi = 0; mi < 4; mi++)
            af[mi] = *(const bf16x8*)(As + (wr * 64 + mi * 16 + lrow) * 32 + lq * 8);
#pragma unroll
        for (int ni = 0; ni < 4; ni++)
            bfr[ni] = *(const bf16x8*)(Bs + (wc * 64 + ni * 16 + lrow) * 32 + lq * 8);
#pragma unroll
        for (int mi = 0; mi < 4; mi++)
#pragma unroll
            for (int ni = 0; ni < 4; ni++)
                acc[mi][ni] = __builtin_amdgcn_mfma_f32_16x16x32_bf16(
                    af[mi], bfr[ni], acc[mi][ni], 0, 0, 0);
        __syncthreads();
    }
}

// GEMM 1: qkv_t[p][o] = sum_c xt[p][c] * w_qkv[o][c]; output bf16, ldc = 1152
// grid (784, 9): m-tiles FAST (stream A, B-tile L2-resident everywhere).
// Epilogue: LDS bounce (rows padded to 136 ushorts) -> 256 B coalesced stores.
__global__ __launch_bounds__(256) void gemm_qkv(
    const unsigned short* __restrict__ A, const unsigned short* __restrict__ Bt,
    unsigned short* __restrict__ C) {
    __shared__ __align__(16) unsigned short smem[2][128 * 32];
    int m0 = blockIdx.x * 128, n0 = blockIdx.y * 128;
    f32x4 acc[4][4];
    gemm_main(A, Bt, m0, n0, smem[0], smem[1], acc);

    int tid = threadIdx.x;
    int lane = tid & 63, wv = tid >> 6;
    int wr = wv >> 1, wc = wv & 1;
    int lrow = lane & 15, lq = lane >> 4;
    unsigned short* epi = smem[0];                       // [32][136] bf16
#pragma unroll
    for (int mi = 0; mi < 4; mi++) {
        int lr = wr * 16 + lq * 4;
#pragma unroll
        for (int ni = 0; ni < 4; ni++)
#pragma unroll
            for (int i = 0; i < 4; i++)
                epi[(lr + i) * 136 + wc * 64 + ni * 16 + lrow] = f2bf(acc[mi][ni][i]);
        __syncthreads();
#pragma unroll
        for (int it = 0; it < 2; it++) {
            int idx = tid + 256 * it;
            int row = idx >> 4, seg = idx & 15;
            uint4 v = *(const uint4*)(epi + row * 136 + seg * 8);
            int grow = m0 + (row >> 4) * 64 + mi * 16 + (row & 15);
            *(uint4*)(&C[(size_t)grow * C3 + n0 + seg * 8]) = v;
        }
        __syncthreads();
    }
}

// GEMM 2: out[b][o][hw] = sum_c w_proj[o][c] * out_t[p][c] + b_proj[o]
// grid (784, 3). Epilogue LDS bounce (fp32, rows padded to 132) -> 512 B runs.
union ProjSmem {
    unsigned short stage[2][128 * 32];
    float epi[32 * 132];
};
__global__ __launch_bounds__(256) void gemm_proj(
    const unsigned short* __restrict__ A, const unsigned short* __restrict__ Bt,
    const float* __restrict__ bias, float* __restrict__ out) {
    __shared__ __align__(16) ProjSmem sm;
    int m0 = blockIdx.y * 128, n0 = blockIdx.x * 128;
    f32x4 acc[4][4];
    gemm_main(A, Bt, m0, n0, sm.stage[0], sm.stage[1], acc);

    int tid = threadIdx.x;
    int lane = tid & 63, wv = tid >> 6;
    int wr = wv >> 1, wc = wv & 1;
    int lrow = lane & 15, lq = lane >> 4;
#pragma unroll
    for (int mi = 0; mi < 4; mi++) {
        int lr = wr * 16 + lq * 4;
#pragma unroll
        for (int ni = 0; ni < 4; ni++) {
            int o = m0 + wr * 64 + mi * 16 + lq * 4;     // row base (i adds)
            (void)o;
#pragma unroll
            for (int i = 0; i < 4; i++)
                sm.epi[(lr + i) * 132 + wc * 64 + ni * 16 + lrow] = acc[mi][ni][i];
        }
        __syncthreads();
#pragma unroll
        for (int it = 0; it < 4; it++) {
            int idx = tid + 256 * it;
            int row = idx >> 5, seg = idx & 31;          // 32 rows x 32 float4-chunks
            f32x4 v = *(const f32x4*)(&sm.epi[row * 132 + seg * 4]);
            int o = m0 + (row >> 4) * 64 + mi * 16 + (row & 15);
            int p = n0 + seg * 4;
            int b = p / HW, hw = p - b * HW;
            float bo = bias[o];
            float4 r;
            r.x = v[0] + bo; r.y = v[1] + bo; r.z = v[2] + bo; r.w = v[3] + bo;
            *(float4*)(&out[((size_t)b * CDIM + o) * HW + hw]) = r;
        }
        __syncthreads();
    }
}

// ---------------------------------------------------------------------------
// Kernel 4: MFMA window attention. grid (2048, 12), block 64 (1 wave).
// ---------------------------------------------------------------------------
__global__ __launch_bounds__(64, 3) void attn_mfma(
    const unsigned short* __restrict__ qkv, const float* __restrict__ bias_t,
    unsigned short* __restrict__ outt) {
    int w = blockIdx.x, h = blockIdx.y;
    int lane = threadIdx.x;
    int q = lane >> 4, c15 = lane & 15;
    int b = w >> 6, wy = (w >> 3) & 7, wx = w & 7;
    int pbase = b * HW + wy * 7 * 56 + wx * 7;

    __shared__ __align__(16) unsigned short sVT[32 * 72];  // V^T[d][key]
    __shared__ __align__(16) unsigned short sP[64 * 72];   // P[query][key]

    int p_t[4]; int valid[4];
#pragma unroll
    for (int t = 0; t < 4; t++) {
        int tok = c15 + 16 * t;
        valid[t] = tok < 49;
        int tc = valid[t] ? tok : 48;
        p_t[t] = pbase + (tc / 7) * 56 + (tc % 7);
    }

    {
        uint4* z = (uint4*)sVT;                   // zero pad columns
#pragma unroll
        for (int i = 0; i < 5; i++) {
            int idx = lane + 64 * i;
            if (idx < 288) z[idx] = (uint4){0u, 0u, 0u, 0u};
        }
    }

    bf16x8 kf[4], qf[4];
#pragma unroll
    for (int t = 0; t < 4; t++) {
        const unsigned short* base = qkv + (size_t)p_t[t] * C3 + h * HD + q * 8;
        qf[t] = *(const bf16x8*)(base);
        kf[t] = *(const bf16x8*)(base + CDIM);
    }

#pragma unroll
    for (int it = 0; it < 4; it++) {
        int c = lane + 64 * it;
        if (c < 196) {
            int tok = c >> 2, s = c & 3;
            int p = pbase + (tok / 7) * 56 + (tok % 7);
            uint4 v = *(const uint4*)(qkv + (size_t)p * C3 + 2 * CDIM + h * HD + s * 8);
            const unsigned short* vp = (const unsigned short*)&v;
#pragma unroll
            for (int i = 0; i < 8; i++)
                sVT[(8 * s + i) * 72 + tok] = vp[i];
        }
    }

    f32x4 acc[4][4];
    const float* bp = bias_t + (size_t)h * 64 * 64;
#pragma unroll
    for (int nt = 0; nt < 4; nt++) {
        const float* bq = bp + (c15 + 16 * nt) * 64 + 4 * q;
#pragma unroll
        for (int mt = 0; mt < 4; mt++)
            acc[mt][nt] = *(const f32x4*)(bq + 16 * mt);
    }

#pragma unroll
    for (int mt = 0; mt < 4; mt++)
#pragma unroll
        for (int nt = 0; nt < 4; nt++)
            acc[mt][nt] = __builtin_amdgcn_mfma_f32_16x16x32_bf16(
                kf[mt], qf[nt], acc[mt][nt], 0, 0, 0);

    const float KSC = 0.25503472f;                // 2^-2.5 * log2(e)
#pragma unroll
    for (int nt = 0; nt < 4; nt++) {
        float mx = acc[0][nt][0];
#pragma unroll
        for (int mt = 0; mt < 4; mt++)
#pragma unroll
            for (int r = 0; r < 4; r++) mx = fmaxf(mx, acc[mt][nt][r]);
        mx = fmaxf(mx, __shfl_xor(mx, 16));
        mx = fmaxf(mx, __shfl_xor(mx, 32));
        float sum = 0.f;
#pragma unroll
        for (int mt = 0; mt < 4; mt++)
#pragma unroll
            for (int r = 0; r < 4; r++) {
                float e = exp2f((acc[mt][nt][r] - mx) * KSC);
                acc[mt][nt][r] = e;
                sum += e;
            }
        sum += __shfl_xor(sum, 16);
        sum += __shfl_xor(sum, 32);
        float inv = 1.0f / sum;
#pragma unroll
        for (int mt = 0; mt < 4; mt++) {
            uint32_t u01 = pk2(acc[mt][nt][0] * inv, acc[mt][nt][1] * inv);
            uint32_t u23 = pk2(acc[mt][nt][2] * inv, acc[mt][nt][3] * inv);
            *(uint2*)(sP + (c15 + 16 * nt) * 72 + 4 * q + 16 * mt) =
                make_uint2(u01, u23);
        }
    }

    bf16x8 pf[4][2], vf[2][2];
#pragma unroll
    for (int nt = 0; nt < 4; nt++)
#pragma unroll
        for (int ks = 0; ks < 2; ks++)
            pf[nt][ks] = *(const bf16x8*)(sP + (c15 + 16 * nt) * 72 + q * 8 + 32 * ks);
#pragma unroll
    for (int mt = 0; mt < 2; mt++)
#pragma unroll
        for (int ks = 0; ks < 2; ks++)
            vf[mt][ks] = *(const bf16x8*)(sVT + (c15 + 16 * mt) * 72 + q * 8 + 32 * ks);

    f32x4 oacc[2][4];
#pragma unroll
    for (int mt = 0; mt < 2; mt++)
#pragma unroll
        for (int nt = 0; nt < 4; nt++)
            oacc[mt][nt] = (f32x4){0.f, 0.f, 0.f, 0.f};
#pragma unroll
    for (int ks = 0; ks < 2; ks++)
#pragma unroll
        for (int mt = 0; mt < 2; mt++)
#pragma unroll
            for (int nt = 0; nt < 4; nt++)
                oacc[mt][nt] = __builtin_amdgcn_mfma_f32_16x16x32_bf16(
                    vf[mt][ks], pf[nt][ks], oacc[mt][nt], 0, 0, 0);

#pragma unroll
    for (int nt = 0; nt < 4; nt++) {
        if (valid[nt]) {
            unsigned short* dst = outt + (size_t)p_t[nt] * CDIM + h * HD + 4 * q;
#pragma unroll
            for (int mt = 0; mt < 2; mt++) {
                uint32_t u01 = pk2(oacc[mt][nt][0], oacc[mt][nt][1]);
                uint32_t u23 = pk2(oacc[mt][nt][2], oacc[mt][nt][3]);
                *(uint2*)(dst + 16 * mt) = make_uint2(u01, u23);
            }
        }
    }
}

// ---------------------------------------------------------------------------
// Launch
// ---------------------------------------------------------------------------
extern "C" void kernel_launch(void* const* d_in, const int* in_sizes, int n_in,
                              void* d_out, int out_size, void* d_ws, size_t ws_size,
                              hipStream_t stream) {
    const float* x      = (const float*)d_in[0];
    const float* w_qkv  = (const float*)d_in[1];
    const float* btab   = (const float*)d_in[2];
    const float* w_proj = (const float*)d_in[3];
    const float* b_proj = (const float*)d_in[4];
    float* out = (float*)d_out;

    char* ws = (char*)d_ws;
    const size_t off_xt   = 0;                         // 77,070,336 (reused as out_t)
    const size_t off_qkv  = 77070336;                  // 231,211,008
    const size_t off_wq   = off_qkv + 231211008;       // 884,736
    const size_t off_wp   = off_wq + 884736;           // 294,912
    const size_t off_bt   = off_wp + 294912;           // 196,608
    unsigned short* xt   = (unsigned short*)(ws + off_xt);
    unsigned short* qkvt = (unsigned short*)(ws + off_qkv);
    unsigned short* wqb  = (unsigned short*)(ws + off_wq);
    unsigned short* wpb  = (unsigned short*)(ws + off_wp);
    float*          bt   = (float*)(ws + off_bt);
    unsigned short* outt = xt;   // alias: xt dead after gemm_qkv

    cvt_f32_bf16<<<(C3 * CDIM / 4 + 255) / 256, 256, 0, stream>>>(w_qkv, wqb, C3 * CDIM / 4);
    cvt_f32_bf16<<<(CDIM * CDIM / 4 + 255) / 256, 256, 0, stream>>>(w_proj, wpb, CDIM * CDIM / 4);
    bias_pre<<<192, 256, 0, stream>>>(btab, bt);
    transpose_x2<<<dim3(49, 6, 32), 256, 0, stream>>>(x, xt);
    gemm_qkv<<<dim3(784, 9), 256, 0, stream>>>(xt, wqb, qkvt);
    attn_mfma<<<dim3(NWIN, NHEAD), 64, 0, stream>>>(qkvt, bt, outt);
    gemm_proj<<<dim3(784, 3), 256, 0, stream>>>(wpb, outt, b_proj, out);
}